// Round 14
// baseline (245.291 us; speedup 1.0000x reference)
//
#include <hip/hip_runtime.h>
#include <stdint.h>

#define N_NODES 100000
#define N_EDGES 1000000
#define NB 782   // ceil(N_NODES/128) buckets of 128 nodes
#define CAP 2048 // arena slots per bucket (expected 1280, sigma 36 -> 21 sigma margin)
#define EPB 2048 // edges per count/scatter block
#define SCB ((N_EDGES + EPB - 1) / EPB)  // 489 (padded to 512 in hcnt/hoff layout)
#define PREPB 6442  // 6250 cast blocks + 192 weight blocks

typedef __attribute__((ext_vector_type(2))) _Float16 f16x2;
typedef __attribute__((ext_vector_type(8))) _Float16 f16x8;
typedef __attribute__((ext_vector_type(4))) float f32x4;

__device__ __forceinline__ unsigned short f2h(float f) {
  _Float16 h = (_Float16)f;
  return *(unsigned short*)&h;
}

// ---------------- pass A: per-block histogram (plain stores, NO global atomics) + prep ----------------
__global__ void k_count_prep(const int* __restrict__ dst, int* __restrict__ hcnt,
                             const float* __restrict__ x, unsigned short* __restrict__ xb,
                             const float* __restrict__ ws0, const float* __restrict__ wn0,
                             unsigned short* __restrict__ wt0,
                             const float* __restrict__ ws1, const float* __restrict__ wn1,
                             unsigned short* __restrict__ wt1,
                             const float* __restrict__ ws2, const float* __restrict__ wn2,
                             unsigned short* __restrict__ wt2) {
  __shared__ int h[NB];
  int t = threadIdx.x;
  if (blockIdx.x < SCB) {
    for (int i = t; i < NB; i += 256) h[i] = 0;
    __syncthreads();
    int base = blockIdx.x * EPB;
#pragma unroll 8
    for (int k = 0; k < EPB / 256; k++) {
      int i = base + t + k * 256;
      if (i < N_EDGES) atomicAdd(&h[dst[i] >> 7], 1);
    }
    __syncthreads();
    int* hrow = hcnt + (size_t)blockIdx.x * NB;  // coalesced 782-int row
    for (int i = t; i < NB; i += 256) hrow[i] = h[i];
    return;
  }
  int b = blockIdx.x - SCB;
  if (b < 6250) {
    int i = b * 256 + t;  // 6250*256 == N_NODES*16 exactly
    float4 a = ((const float4*)x)[2 * i];
    float4 v = ((const float4*)x)[2 * i + 1];
    unsigned short r[8] = {f2h(a.x), f2h(a.y), f2h(a.z), f2h(a.w),
                           f2h(v.x), f2h(v.y), f2h(v.z), f2h(v.w)};
    *(uint4*)(xb + (size_t)i * 8) = *(uint4*)r;
    return;
  }
  int w = (b - 6250) * 256 + t;  // 0 .. 49151
  if (w < 16384) {  // wt0: [n][256] = [Ws0^T | Wn0^T]
    int n = w >> 7, k = w & 127;
    wt0[n * 256 + k] = f2h(ws0[(size_t)k * 128 + n]);
    wt0[n * 256 + 128 + k] = f2h(wn0[(size_t)k * 128 + n]);
  } else if (w < 32768) {  // wt1
    w -= 16384;
    int n = w >> 7, k = w & 127;
    wt1[n * 256 + k] = f2h(ws1[(size_t)k * 128 + n]);
    wt1[n * 256 + 128 + k] = f2h(wn1[(size_t)k * 128 + n]);
  } else {  // wt2: [n][128], n<64 -> Ws2 col n ; n>=64 -> Wn2 col n-64 (K=128)
    w -= 32768;
    int n = w >> 7, k = w & 127;
    float v = (n < 64) ? ws2[(size_t)k * 64 + n] : wn2[(size_t)k * 64 + (n - 64)];
    wt2[n * 128 + k] = f2h(v);
  }
}

// ---------------- pass B: per-bucket exclusive scan across blocks -> cursors + totals ----------------
// one block per bucket; scans the 489 per-block counts (pad to 512).
__global__ __launch_bounds__(512) void k_hscan(const int* __restrict__ hcnt,
                                               int* __restrict__ hoff,
                                               int* __restrict__ bcnt) {
  __shared__ int sc[512];
  int bucket = blockIdx.x, t = threadIdx.x;
  int v = (t < SCB) ? hcnt[(size_t)t * NB + bucket] : 0;
  sc[t] = v;
  __syncthreads();
  for (int off = 1; off < 512; off <<= 1) {
    int a = (t >= off) ? sc[t - off] : 0;
    __syncthreads();
    sc[t] += a;
    __syncthreads();
  }
  hoff[(size_t)bucket * 512 + t] = sc[t] - v;  // exclusive prefix, coalesced
  if (t == 511) bcnt[bucket] = sc[511];
}

// ---------------- pass C: scatter into chunked arena (cursors from hoff, LDS-only atomics) ----------------
__global__ void k_scatter(const int* __restrict__ src, const int* __restrict__ dst,
                          const int* __restrict__ hoff, unsigned int* __restrict__ stage) {
  __shared__ int cur[NB];
  int t = threadIdx.x;
  int blk = blockIdx.x;
  for (int i = t; i < NB; i += 256) cur[i] = hoff[(size_t)i * 512 + blk];
  __syncthreads();
  int base = blk * EPB;
#pragma unroll 8
  for (int k = 0; k < EPB / 256; k++) {
    int i = base + t + k * 256;
    if (i < N_EDGES) {
      int d = dst[i];
      int b = d >> 7;
      int pos = atomicAdd(&cur[b], 1);
      stage[(size_t)b * CAP + pos] = ((unsigned int)(d & 127) << 17) | (unsigned int)src[i];
    }
  }
}

// ---------------- per-bucket: group by node within arena chunk ----------------
__global__ void k_bucket(const unsigned int* __restrict__ stage, const int* __restrict__ bcnt,
                         int* __restrict__ csr, int* __restrict__ rowbeg,
                         int* __restrict__ rowend, float* __restrict__ dinv) {
  __shared__ int cnt[128], sc[128], cur[128];
  int b = blockIdx.x, t = threadIdx.x;
  int nb = bcnt[b];
  const unsigned int* sb = stage + (size_t)b * CAP;
  int e0 = b * CAP;
  if (t < 128) cnt[t] = 0;
  __syncthreads();
  for (int e = t; e < nb; e += 256)
    atomicAdd(&cnt[sb[e] >> 17], 1);
  __syncthreads();
  int myc = (t < 128) ? cnt[t] : 0;
  if (t < 128) sc[t] = myc;
  __syncthreads();
  for (int off = 1; off < 128; off <<= 1) {
    int a = (t < 128 && t >= off) ? sc[t - off] : 0;
    __syncthreads();
    if (t < 128) sc[t] += a;
    __syncthreads();
  }
  if (t < 128) {
    int node = b * 128 + t;
    int ex = sc[t] - myc;
    cur[t] = ex;
    if (node < N_NODES) {
      rowbeg[node] = e0 + ex;
      rowend[node] = e0 + ex + myc;
      dinv[node] = myc ? 1.0f / (float)myc : 0.0f;
    }
  }
  __syncthreads();
  for (int e = t; e < nb; e += 256) {
    unsigned int v = sb[e];
    int l = v >> 17;
    int pos = e0 + atomicAdd(&cur[l], 1);
    csr[pos] = (int)(v & 0x1FFFFu);
  }
}

// ---------------- aggregation (128-dim f16 rows): wave/node, 16 slots ----------------
// 1024-thread blocks (16 waves, grid 6250, zero tail): fewer workgroups for
// denser CU packing; per-wave structure identical to the measured-good R9 form.
__global__ __launch_bounds__(1024) void k_agg(
    const unsigned short* __restrict__ feat,
    const int* __restrict__ rowbeg, const int* __restrict__ rowend,
    const int* __restrict__ csr,
    const float* __restrict__ dinv, unsigned short* __restrict__ nm) {
  int wv = threadIdx.x >> 6, lane = threadIdx.x & 63;
  int node = blockIdx.x * 16 + wv;
  if (node >= N_NODES) return;
  const uint4* fp = (const uint4*)feat;  // 16 uint4 per feature row
  int s0 = rowbeg[node], s1 = rowend[node];
  int g = lane >> 4, c = lane & 15;
  f16x2 q0 = {0, 0}, q1 = {0, 0}, q2 = {0, 0}, q3 = {0, 0};
  for (int j = s0 + g; j < s1; j += 16) {
    int i1 = j + 4, i2 = j + 8, i3 = j + 12;
    bool h1 = i1 < s1, h2 = i2 < s1, h3 = i3 < s1;
    int c0 = csr[j];
    int c1 = h1 ? csr[i1] : 0;
    int c2 = h2 ? csr[i2] : 0;
    int c3 = h3 ? csr[i3] : 0;
    uint4 v0, v1, v2, v3;
    v0 = fp[(size_t)c0 * 16 + c];
    if (h1) v1 = fp[(size_t)c1 * 16 + c];
    if (h2) v2 = fp[(size_t)c2 * 16 + c];
    if (h3) v3 = fp[(size_t)c3 * 16 + c];
    q0 += *(const f16x2*)&v0.x; q1 += *(const f16x2*)&v0.y;
    q2 += *(const f16x2*)&v0.z; q3 += *(const f16x2*)&v0.w;
    if (h1) {
      q0 += *(const f16x2*)&v1.x; q1 += *(const f16x2*)&v1.y;
      q2 += *(const f16x2*)&v1.z; q3 += *(const f16x2*)&v1.w;
    }
    if (h2) {
      q0 += *(const f16x2*)&v2.x; q1 += *(const f16x2*)&v2.y;
      q2 += *(const f16x2*)&v2.z; q3 += *(const f16x2*)&v2.w;
    }
    if (h3) {
      q0 += *(const f16x2*)&v3.x; q1 += *(const f16x2*)&v3.y;
      q2 += *(const f16x2*)&v3.z; q3 += *(const f16x2*)&v3.w;
    }
  }
  float a0 = (float)q0[0], a1 = (float)q0[1], a2 = (float)q1[0], a3 = (float)q1[1];
  float a4 = (float)q2[0], a5 = (float)q2[1], a6 = (float)q3[0], a7 = (float)q3[1];
#define RED(x) x += __shfl_xor(x, 16); x += __shfl_xor(x, 32);
  RED(a0) RED(a1) RED(a2) RED(a3) RED(a4) RED(a5) RED(a6) RED(a7)
#undef RED
  if (g == 0) {
    float di = dinv[node];
    uint4 o;
    o.x = ((unsigned int)f2h(a1 * di) << 16) | (unsigned int)f2h(a0 * di);
    o.y = ((unsigned int)f2h(a3 * di) << 16) | (unsigned int)f2h(a2 * di);
    o.z = ((unsigned int)f2h(a5 * di) << 16) | (unsigned int)f2h(a4 * di);
    o.w = ((unsigned int)f2h(a7 * di) << 16) | (unsigned int)f2h(a6 * di);
    ((uint4*)(nm + (size_t)node * 128))[c] = o;
  }
}

// ---------------- layer-2 aggregation of z (64-dim f16 rows) + self add, fp32 out ----------------
__global__ __launch_bounds__(1024) void k_agg2(
    const unsigned short* __restrict__ zn,
    const int* __restrict__ rowbeg, const int* __restrict__ rowend,
    const int* __restrict__ csr, const float* __restrict__ dinv,
    const float* __restrict__ self2, float* __restrict__ out) {
  int wv = threadIdx.x >> 6, lane = threadIdx.x & 63;
  int node = blockIdx.x * 16 + wv;
  if (node >= N_NODES) return;
  const uint4* fp = (const uint4*)zn;  // 8 uint4 per row
  int s0 = rowbeg[node], s1 = rowend[node];
  int g = lane >> 3, c = lane & 7;
  f16x2 q0 = {0, 0}, q1 = {0, 0}, q2 = {0, 0}, q3 = {0, 0};
  for (int j = s0 + g; j < s1; j += 32) {
    int i1 = j + 8, i2 = j + 16, i3 = j + 24;
    bool h1 = i1 < s1, h2 = i2 < s1, h3 = i3 < s1;
    int c0 = csr[j];
    int c1 = h1 ? csr[i1] : 0;
    int c2 = h2 ? csr[i2] : 0;
    int c3 = h3 ? csr[i3] : 0;
    uint4 v0, v1, v2, v3;
    v0 = fp[(size_t)c0 * 8 + c];
    if (h1) v1 = fp[(size_t)c1 * 8 + c];
    if (h2) v2 = fp[(size_t)c2 * 8 + c];
    if (h3) v3 = fp[(size_t)c3 * 8 + c];
    q0 += *(const f16x2*)&v0.x; q1 += *(const f16x2*)&v0.y;
    q2 += *(const f16x2*)&v0.z; q3 += *(const f16x2*)&v0.w;
    if (h1) {
      q0 += *(const f16x2*)&v1.x; q1 += *(const f16x2*)&v1.y;
      q2 += *(const f16x2*)&v1.z; q3 += *(const f16x2*)&v1.w;
    }
    if (h2) {
      q0 += *(const f16x2*)&v2.x; q1 += *(const f16x2*)&v2.y;
      q2 += *(const f16x2*)&v2.z; q3 += *(const f16x2*)&v2.w;
    }
    if (h3) {
      q0 += *(const f16x2*)&v3.x; q1 += *(const f16x2*)&v3.y;
      q2 += *(const f16x2*)&v3.z; q3 += *(const f16x2*)&v3.w;
    }
  }
  float a0 = (float)q0[0], a1 = (float)q0[1], a2 = (float)q1[0], a3 = (float)q1[1];
  float a4 = (float)q2[0], a5 = (float)q2[1], a6 = (float)q3[0], a7 = (float)q3[1];
#define RED8(x) x += __shfl_xor(x, 8); x += __shfl_xor(x, 16); x += __shfl_xor(x, 32);
  RED8(a0) RED8(a1) RED8(a2) RED8(a3) RED8(a4) RED8(a5) RED8(a6) RED8(a7)
#undef RED8
  if (g == 0) {
    float di = dinv[node];
    const float4* sp = (const float4*)(self2 + (size_t)node * 64);
    float4 s0v = sp[c * 2], s1v = sp[c * 2 + 1];
    float4 o0 = {s0v.x + a0 * di, s0v.y + a1 * di, s0v.z + a2 * di, s0v.w + a3 * di};
    float4 o1 = {s1v.x + a4 * di, s1v.y + a5 * di, s1v.z + a6 * di, s1v.w + a7 * di};
    float4* op = (float4*)(out + (size_t)node * 64);
    op[c * 2] = o0;
    op[c * 2 + 1] = o1;
  }
}

// ---------------- MFMA GEMM (f16): OUT = act([A0|A1] @ WT^T + B), layers 0/1 ----------------
template <int NOUT, bool RELU>
__global__ __launch_bounds__(256, 4) void k_mm(
    const unsigned short* __restrict__ A0, const unsigned short* __restrict__ A1,
    const unsigned short* __restrict__ WT, const float* __restrict__ Bv,
    unsigned short* __restrict__ OUT) {
  constexpr int NFC = NOUT / 64;
  __shared__ __align__(16) unsigned short sm[16896];  // 33792 B
  const int row0 = blockIdx.x * 64;
  const int tid = threadIdx.x;

  for (int i = tid; i < 1024; i += 256) {
    int r = i >> 4, c = i & 15;
    int gr = row0 + r;
    if (gr >= N_NODES) gr = N_NODES - 1;
    *(uint4*)(sm + r * 264 + c * 8) = ((const uint4*)(A0 + (size_t)gr * 128))[c];
    *(uint4*)(sm + r * 264 + 128 + c * 8) = ((const uint4*)(A1 + (size_t)gr * 128))[c];
  }

  const int lane = tid & 63;
  const int w = tid >> 6;
  const int r16 = lane & 15;
  const int kg = lane >> 4;
  const int wc0 = w * (NOUT / 4);

  f32x4 acc[4][NFC];
#pragma unroll
  for (int rf = 0; rf < 4; rf++)
#pragma unroll
    for (int cf = 0; cf < NFC; cf++) acc[rf][cf] = (f32x4){0.f, 0.f, 0.f, 0.f};

  __syncthreads();

  const unsigned short* wtb = WT + (size_t)(wc0 + r16) * 256 + kg * 8;
  const unsigned short* asb = sm + r16 * 264 + kg * 8;

  for (int ks = 0; ks < 8; ks++) {
    f16x8 a[4];
#pragma unroll
    for (int rf = 0; rf < 4; rf++)
      a[rf] = *(const f16x8*)(asb + rf * 16 * 264 + ks * 32);
#pragma unroll
    for (int cf = 0; cf < NFC; cf++) {
      f16x8 b = *(const f16x8*)(wtb + cf * 16 * 256 + ks * 32);
#pragma unroll
      for (int rf = 0; rf < 4; rf++)
        acc[rf][cf] = __builtin_amdgcn_mfma_f32_16x16x32_f16(a[rf], b, acc[rf][cf], 0, 0, 0);
    }
  }

  __syncthreads();  // reuse sm for output staging

  constexpr int LSO = NOUT + 8;
  unsigned short* so = sm;
#pragma unroll
  for (int rf = 0; rf < 4; rf++)
#pragma unroll
    for (int cf = 0; cf < NFC; cf++) {
      int col = wc0 + cf * 16 + r16;
      float bias = Bv[col];
#pragma unroll
      for (int r = 0; r < 4; r++) {
        int row = rf * 16 + kg * 4 + r;
        float v = acc[rf][cf][r] + bias;
        if (RELU) v = fmaxf(v, 0.f);
        so[row * LSO + col] = f2h(v);
      }
    }
  __syncthreads();
  for (int i = tid; i < 64 * (NOUT / 8); i += 256) {
    int r = i / (NOUT / 8), c = i % (NOUT / 8);
    int gr = row0 + r;
    if (gr < N_NODES)
      *(uint4*)(OUT + (size_t)gr * NOUT + c * 8) = *(const uint4*)(so + r * LSO + c * 8);
  }
}

// ---------------- layer-2 GEMM: h2 (K=128) @ [Ws2|Wn2] -> self2 (fp32,+bias) & zn (f16) ----------------
__global__ __launch_bounds__(256, 4) void k_mm2(
    const unsigned short* __restrict__ A, const unsigned short* __restrict__ WT,
    const float* __restrict__ Bv, float* __restrict__ SELF,
    unsigned short* __restrict__ ZN) {
  __shared__ __align__(16) unsigned short sm[64 * 136];  // 17408 B
  const int row0 = blockIdx.x * 64;
  const int tid = threadIdx.x;

  for (int i = tid; i < 1024; i += 256) {
    int r = i >> 4, c = i & 15;
    int gr = row0 + r;
    if (gr >= N_NODES) gr = N_NODES - 1;
    *(uint4*)(sm + r * 136 + c * 8) = ((const uint4*)(A + (size_t)gr * 128))[c];
  }

  const int lane = tid & 63;
  const int w = tid >> 6;
  const int r16 = lane & 15;
  const int kg = lane >> 4;
  const int wc0 = w * 32;

  f32x4 acc[4][2];
#pragma unroll
  for (int rf = 0; rf < 4; rf++)
#pragma unroll
    for (int cf = 0; cf < 2; cf++) acc[rf][cf] = (f32x4){0.f, 0.f, 0.f, 0.f};

  __syncthreads();

  const unsigned short* wtb = WT + (size_t)(wc0 + r16) * 128 + kg * 8;
  const unsigned short* asb = sm + r16 * 136 + kg * 8;

  for (int ks = 0; ks < 4; ks++) {
    f16x8 a[4];
#pragma unroll
    for (int rf = 0; rf < 4; rf++)
      a[rf] = *(const f16x8*)(asb + rf * 16 * 136 + ks * 32);
#pragma unroll
    for (int cf = 0; cf < 2; cf++) {
      f16x8 b = *(const f16x8*)(wtb + cf * 16 * 128 + ks * 32);
#pragma unroll
      for (int rf = 0; rf < 4; rf++)
        acc[rf][cf] = __builtin_amdgcn_mfma_f32_16x16x32_f16(a[rf], b, acc[rf][cf], 0, 0, 0);
    }
  }

  __syncthreads();

  // phase A: self (cols 0..63) fp32 + bias, staged [64][68] floats
  float* sof = (float*)sm;
#pragma unroll
  for (int rf = 0; rf < 4; rf++)
#pragma unroll
    for (int cf = 0; cf < 2; cf++) {
      int col = wc0 + cf * 16 + r16;
      if (col < 64) {
        float bias = Bv[col];
#pragma unroll
        for (int r = 0; r < 4; r++) {
          int row = rf * 16 + kg * 4 + r;
          sof[row * 68 + col] = acc[rf][cf][r] + bias;
        }
      }
    }
  __syncthreads();
  for (int i = tid; i < 1024; i += 256) {
    int r = i >> 4, c = i & 15;
    int gr = row0 + r;
    if (gr < N_NODES)
      *(float4*)(SELF + (size_t)gr * 64 + c * 4) = *(const float4*)(sof + r * 68 + c * 4);
  }
  __syncthreads();

  // phase B: zn (cols 64..127) f16, staged [64][72] ushort
  unsigned short* soh = sm;
#pragma unroll
  for (int rf = 0; rf < 4; rf++)
#pragma unroll
    for (int cf = 0; cf < 2; cf++) {
      int col = wc0 + cf * 16 + r16;
      if (col >= 64) {
#pragma unroll
        for (int r = 0; r < 4; r++) {
          int row = rf * 16 + kg * 4 + r;
          soh[row * 72 + (col - 64)] = f2h(acc[rf][cf][r]);
        }
      }
    }
  __syncthreads();
  for (int i = tid; i < 512; i += 256) {
    int r = i >> 3, c = i & 7;
    int gr = row0 + r;
    if (gr < N_NODES)
      *(uint4*)(ZN + (size_t)gr * 64 + c * 8) = *(const uint4*)(soh + r * 72 + c * 8);
  }
}

// ---------------- launch ----------------

extern "C" void kernel_launch(void* const* d_in, const int* in_sizes, int n_in,
                              void* d_out, int out_size, void* d_ws, size_t ws_size,
                              hipStream_t stream) {
  const float* x   = (const float*)d_in[0];
  const int*   src = (const int*)d_in[1];
  const int*   dst = (const int*)d_in[2];
  const float* ws0 = (const float*)d_in[3];
  const float* wn0 = (const float*)d_in[4];
  const float* b0  = (const float*)d_in[5];
  const float* ws1 = (const float*)d_in[6];
  const float* wn1 = (const float*)d_in[7];
  const float* b1  = (const float*)d_in[8];
  const float* ws2 = (const float*)d_in[9];
  const float* wn2 = (const float*)d_in[10];
  const float* b2  = (const float*)d_in[11];
  float* out = (float*)d_out;

  uint8_t* base = (uint8_t*)d_ws;
  size_t off = 0;
  auto alloc = [&](size_t bytes) -> void* {
    void* p = base + off;
    off = (off + bytes + 255) & ~(size_t)255;
    return p;
  };
  int*   rowbeg  = (int*)alloc((size_t)N_NODES * 4);
  int*   rowend  = (int*)alloc((size_t)N_NODES * 4);
  float* dinv    = (float*)alloc((size_t)N_NODES * 4);
  int*   csr     = (int*)alloc((size_t)NB * CAP * 4);            // 6.4 MB arena
  unsigned int* stage = (unsigned int*)alloc((size_t)NB * CAP * 4);
  int*   hcnt    = (int*)alloc((size_t)512 * NB * 4);            // [blk][bucket]
  int*   hoff    = (int*)alloc((size_t)NB * 512 * 4);            // [bucket][blk]
  int*   bcnt    = (int*)alloc((size_t)NB * 4);
  unsigned short* xb  = (unsigned short*)alloc((size_t)N_NODES * 128 * 2);
  unsigned short* nmb = (unsigned short*)alloc((size_t)N_NODES * 128 * 2);
  unsigned short* h1b = (unsigned short*)alloc((size_t)N_NODES * 128 * 2);
  unsigned short* h2b = (unsigned short*)alloc((size_t)N_NODES * 128 * 2);
  float* self2 = (float*)alloc((size_t)N_NODES * 64 * 4);
  unsigned short* znb = (unsigned short*)alloc((size_t)N_NODES * 64 * 2);
  unsigned short* wt0 = (unsigned short*)alloc(128 * 256 * 2);
  unsigned short* wt1 = (unsigned short*)alloc(128 * 256 * 2);
  unsigned short* wt2 = (unsigned short*)alloc(128 * 128 * 2);

  k_count_prep<<<SCB + PREPB, 256, 0, stream>>>(dst, hcnt, x, xb, ws0, wn0, wt0,
                                                ws1, wn1, wt1, ws2, wn2, wt2);
  k_hscan<<<NB, 512, 0, stream>>>(hcnt, hoff, bcnt);
  k_scatter<<<SCB, 256, 0, stream>>>(src, dst, hoff, stage);
  k_bucket<<<NB, 256, 0, stream>>>(stage, bcnt, csr, rowbeg, rowend, dinv);

  const int GMM = (N_NODES + 63) / 64;  // 1563
  const int GAGG = N_NODES / 16;        // 6250 (exact)

  // layer 0
  k_agg<<<GAGG, 1024, 0, stream>>>(xb, rowbeg, rowend, csr, dinv, nmb);
  k_mm<128, true><<<GMM, 256, 0, stream>>>(xb, nmb, wt0, b0, h1b);
  // layer 1
  k_agg<<<GAGG, 1024, 0, stream>>>(h1b, rowbeg, rowend, csr, dinv, nmb);
  k_mm<128, true><<<GMM, 256, 0, stream>>>(h1b, nmb, wt1, b1, h2b);
  // layer 2: transform-then-aggregate (linearity of mean)
  k_mm2<<<GMM, 256, 0, stream>>>(h2b, wt2, b2, self2, znb);
  k_agg2<<<GAGG, 1024, 0, stream>>>(znb, rowbeg, rowend, csr, dinv, self2, out);
}

// Round 15
// 234.062 us; speedup vs baseline: 1.0480x; 1.0480x over previous
//
#include <hip/hip_runtime.h>
#include <stdint.h>

#define N_NODES 100000
#define N_EDGES 1000000
#define NB 782   // ceil(N_NODES/128) buckets of 128 nodes
#define CAP 2048 // arena slots per bucket (expected 1280, sigma 36 -> 21 sigma margin)
#define EPB 2048 // edges per count/scatter block
#define SCB ((N_EDGES + EPB - 1) / EPB)  // 489 (padded to 512 in hcnt/hoff layout)
#define PREPB 6442  // 6250 cast blocks + 192 weight blocks

typedef __attribute__((ext_vector_type(2))) _Float16 f16x2;
typedef __attribute__((ext_vector_type(8))) _Float16 f16x8;
typedef __attribute__((ext_vector_type(4))) float f32x4;

__device__ __forceinline__ unsigned short f2h(float f) {
  _Float16 h = (_Float16)f;
  return *(unsigned short*)&h;
}

// ---------------- pass A: per-block histogram (plain stores, NO global atomics) + prep ----------------
__global__ void k_count_prep(const int* __restrict__ dst, int* __restrict__ hcnt,
                             const float* __restrict__ x, unsigned short* __restrict__ xb,
                             const float* __restrict__ ws0, const float* __restrict__ wn0,
                             unsigned short* __restrict__ wt0,
                             const float* __restrict__ ws1, const float* __restrict__ wn1,
                             unsigned short* __restrict__ wt1,
                             const float* __restrict__ ws2, const float* __restrict__ wn2,
                             unsigned short* __restrict__ wt2) {
  __shared__ int h[NB];
  int t = threadIdx.x;
  if (blockIdx.x < SCB) {
    for (int i = t; i < NB; i += 256) h[i] = 0;
    __syncthreads();
    int base = blockIdx.x * EPB;
#pragma unroll 8
    for (int k = 0; k < EPB / 256; k++) {
      int i = base + t + k * 256;
      if (i < N_EDGES) atomicAdd(&h[dst[i] >> 7], 1);
    }
    __syncthreads();
    int* hrow = hcnt + (size_t)blockIdx.x * NB;  // coalesced 782-int row
    for (int i = t; i < NB; i += 256) hrow[i] = h[i];
    return;
  }
  int b = blockIdx.x - SCB;
  if (b < 6250) {
    int i = b * 256 + t;  // 6250*256 == N_NODES*16 exactly
    float4 a = ((const float4*)x)[2 * i];
    float4 v = ((const float4*)x)[2 * i + 1];
    unsigned short r[8] = {f2h(a.x), f2h(a.y), f2h(a.z), f2h(a.w),
                           f2h(v.x), f2h(v.y), f2h(v.z), f2h(v.w)};
    *(uint4*)(xb + (size_t)i * 8) = *(uint4*)r;
    return;
  }
  int w = (b - 6250) * 256 + t;  // 0 .. 49151
  if (w < 16384) {  // wt0: [n][256] = [Ws0^T | Wn0^T]
    int n = w >> 7, k = w & 127;
    wt0[n * 256 + k] = f2h(ws0[(size_t)k * 128 + n]);
    wt0[n * 256 + 128 + k] = f2h(wn0[(size_t)k * 128 + n]);
  } else if (w < 32768) {  // wt1
    w -= 16384;
    int n = w >> 7, k = w & 127;
    wt1[n * 256 + k] = f2h(ws1[(size_t)k * 128 + n]);
    wt1[n * 256 + 128 + k] = f2h(wn1[(size_t)k * 128 + n]);
  } else {  // wt2: [n][128], n<64 -> Ws2 col n ; n>=64 -> Wn2 col n-64 (K=128)
    w -= 32768;
    int n = w >> 7, k = w & 127;
    float v = (n < 64) ? ws2[(size_t)k * 64 + n] : wn2[(size_t)k * 64 + (n - 64)];
    wt2[n * 128 + k] = f2h(v);
  }
}

// ---------------- pass B: per-bucket exclusive scan across blocks -> cursors + totals ----------------
__global__ __launch_bounds__(512) void k_hscan(const int* __restrict__ hcnt,
                                               int* __restrict__ hoff,
                                               int* __restrict__ bcnt) {
  __shared__ int sc[512];
  int bucket = blockIdx.x, t = threadIdx.x;
  int v = (t < SCB) ? hcnt[(size_t)t * NB + bucket] : 0;
  sc[t] = v;
  __syncthreads();
  for (int off = 1; off < 512; off <<= 1) {
    int a = (t >= off) ? sc[t - off] : 0;
    __syncthreads();
    sc[t] += a;
    __syncthreads();
  }
  hoff[(size_t)bucket * 512 + t] = sc[t] - v;  // exclusive prefix, coalesced
  if (t == 511) bcnt[bucket] = sc[511];
}

// ---------------- pass C: scatter into chunked arena (cursors from hoff, LDS-only atomics) ----------------
__global__ void k_scatter(const int* __restrict__ src, const int* __restrict__ dst,
                          const int* __restrict__ hoff, unsigned int* __restrict__ stage) {
  __shared__ int cur[NB];
  int t = threadIdx.x;
  int blk = blockIdx.x;
  for (int i = t; i < NB; i += 256) cur[i] = hoff[(size_t)i * 512 + blk];
  __syncthreads();
  int base = blk * EPB;
#pragma unroll 8
  for (int k = 0; k < EPB / 256; k++) {
    int i = base + t + k * 256;
    if (i < N_EDGES) {
      int d = dst[i];
      int b = d >> 7;
      int pos = atomicAdd(&cur[b], 1);
      stage[(size_t)b * CAP + pos] = ((unsigned int)(d & 127) << 17) | (unsigned int)src[i];
    }
  }
}

// ---------------- per-bucket: group by node within arena chunk ----------------
__global__ void k_bucket(const unsigned int* __restrict__ stage, const int* __restrict__ bcnt,
                         int* __restrict__ csr, int* __restrict__ rowbeg,
                         int* __restrict__ rowend, float* __restrict__ dinv) {
  __shared__ int cnt[128], sc[128], cur[128];
  int b = blockIdx.x, t = threadIdx.x;
  int nb = bcnt[b];
  const unsigned int* sb = stage + (size_t)b * CAP;
  int e0 = b * CAP;
  if (t < 128) cnt[t] = 0;
  __syncthreads();
  for (int e = t; e < nb; e += 256)
    atomicAdd(&cnt[sb[e] >> 17], 1);
  __syncthreads();
  int myc = (t < 128) ? cnt[t] : 0;
  if (t < 128) sc[t] = myc;
  __syncthreads();
  for (int off = 1; off < 128; off <<= 1) {
    int a = (t < 128 && t >= off) ? sc[t - off] : 0;
    __syncthreads();
    if (t < 128) sc[t] += a;
    __syncthreads();
  }
  if (t < 128) {
    int node = b * 128 + t;
    int ex = sc[t] - myc;
    cur[t] = ex;
    if (node < N_NODES) {
      rowbeg[node] = e0 + ex;
      rowend[node] = e0 + ex + myc;
      dinv[node] = myc ? 1.0f / (float)myc : 0.0f;
    }
  }
  __syncthreads();
  for (int e = t; e < nb; e += 256) {
    unsigned int v = sb[e];
    int l = v >> 17;
    int pos = e0 + atomicAdd(&cur[l], 1);
    csr[pos] = (int)(v & 0x1FFFFu);
  }
}

// ---------------- aggregation (128-dim f16 rows): wave/node, 16 slots ----------------
// 256-thread blocks, one wave per node (R14 lesson: 1024-thread blocks hold a
// 16-wave slot until the slowest wave retires -> occupancy 66->58%, 42.6->46us)
__global__ void k_agg(const unsigned short* __restrict__ feat,
                      const int* __restrict__ rowbeg, const int* __restrict__ rowend,
                      const int* __restrict__ csr,
                      const float* __restrict__ dinv, unsigned short* __restrict__ nm) {
  int wv = threadIdx.x >> 6, lane = threadIdx.x & 63;
  int node = blockIdx.x * 4 + wv;
  if (node >= N_NODES) return;
  const uint4* fp = (const uint4*)feat;  // 16 uint4 per feature row
  int s0 = rowbeg[node], s1 = rowend[node];
  int g = lane >> 4, c = lane & 15;
  f16x2 q0 = {0, 0}, q1 = {0, 0}, q2 = {0, 0}, q3 = {0, 0};
  for (int j = s0 + g; j < s1; j += 16) {
    int i1 = j + 4, i2 = j + 8, i3 = j + 12;
    bool h1 = i1 < s1, h2 = i2 < s1, h3 = i3 < s1;
    int c0 = csr[j];
    int c1 = h1 ? csr[i1] : 0;
    int c2 = h2 ? csr[i2] : 0;
    int c3 = h3 ? csr[i3] : 0;
    uint4 v0, v1, v2, v3;
    v0 = fp[(size_t)c0 * 16 + c];
    if (h1) v1 = fp[(size_t)c1 * 16 + c];
    if (h2) v2 = fp[(size_t)c2 * 16 + c];
    if (h3) v3 = fp[(size_t)c3 * 16 + c];
    q0 += *(const f16x2*)&v0.x; q1 += *(const f16x2*)&v0.y;
    q2 += *(const f16x2*)&v0.z; q3 += *(const f16x2*)&v0.w;
    if (h1) {
      q0 += *(const f16x2*)&v1.x; q1 += *(const f16x2*)&v1.y;
      q2 += *(const f16x2*)&v1.z; q3 += *(const f16x2*)&v1.w;
    }
    if (h2) {
      q0 += *(const f16x2*)&v2.x; q1 += *(const f16x2*)&v2.y;
      q2 += *(const f16x2*)&v2.z; q3 += *(const f16x2*)&v2.w;
    }
    if (h3) {
      q0 += *(const f16x2*)&v3.x; q1 += *(const f16x2*)&v3.y;
      q2 += *(const f16x2*)&v3.z; q3 += *(const f16x2*)&v3.w;
    }
  }
  float a0 = (float)q0[0], a1 = (float)q0[1], a2 = (float)q1[0], a3 = (float)q1[1];
  float a4 = (float)q2[0], a5 = (float)q2[1], a6 = (float)q3[0], a7 = (float)q3[1];
#define RED(x) x += __shfl_xor(x, 16); x += __shfl_xor(x, 32);
  RED(a0) RED(a1) RED(a2) RED(a3) RED(a4) RED(a5) RED(a6) RED(a7)
#undef RED
  if (g == 0) {
    float di = dinv[node];
    uint4 o;
    o.x = ((unsigned int)f2h(a1 * di) << 16) | (unsigned int)f2h(a0 * di);
    o.y = ((unsigned int)f2h(a3 * di) << 16) | (unsigned int)f2h(a2 * di);
    o.z = ((unsigned int)f2h(a5 * di) << 16) | (unsigned int)f2h(a4 * di);
    o.w = ((unsigned int)f2h(a7 * di) << 16) | (unsigned int)f2h(a6 * di);
    ((uint4*)(nm + (size_t)node * 128))[c] = o;
  }
}

// ---------------- layer-2 aggregation of z (64-dim f16 rows) + self add, fp32 out ----------------
__global__ void k_agg2(const unsigned short* __restrict__ zn,
                       const int* __restrict__ rowbeg, const int* __restrict__ rowend,
                       const int* __restrict__ csr, const float* __restrict__ dinv,
                       const float* __restrict__ self2, float* __restrict__ out) {
  int wv = threadIdx.x >> 6, lane = threadIdx.x & 63;
  int node = blockIdx.x * 4 + wv;
  if (node >= N_NODES) return;
  const uint4* fp = (const uint4*)zn;  // 8 uint4 per row
  int s0 = rowbeg[node], s1 = rowend[node];
  int g = lane >> 3, c = lane & 7;
  f16x2 q0 = {0, 0}, q1 = {0, 0}, q2 = {0, 0}, q3 = {0, 0};
  for (int j = s0 + g; j < s1; j += 32) {
    int i1 = j + 8, i2 = j + 16, i3 = j + 24;
    bool h1 = i1 < s1, h2 = i2 < s1, h3 = i3 < s1;
    int c0 = csr[j];
    int c1 = h1 ? csr[i1] : 0;
    int c2 = h2 ? csr[i2] : 0;
    int c3 = h3 ? csr[i3] : 0;
    uint4 v0, v1, v2, v3;
    v0 = fp[(size_t)c0 * 8 + c];
    if (h1) v1 = fp[(size_t)c1 * 8 + c];
    if (h2) v2 = fp[(size_t)c2 * 8 + c];
    if (h3) v3 = fp[(size_t)c3 * 8 + c];
    q0 += *(const f16x2*)&v0.x; q1 += *(const f16x2*)&v0.y;
    q2 += *(const f16x2*)&v0.z; q3 += *(const f16x2*)&v0.w;
    if (h1) {
      q0 += *(const f16x2*)&v1.x; q1 += *(const f16x2*)&v1.y;
      q2 += *(const f16x2*)&v1.z; q3 += *(const f16x2*)&v1.w;
    }
    if (h2) {
      q0 += *(const f16x2*)&v2.x; q1 += *(const f16x2*)&v2.y;
      q2 += *(const f16x2*)&v2.z; q3 += *(const f16x2*)&v2.w;
    }
    if (h3) {
      q0 += *(const f16x2*)&v3.x; q1 += *(const f16x2*)&v3.y;
      q2 += *(const f16x2*)&v3.z; q3 += *(const f16x2*)&v3.w;
    }
  }
  float a0 = (float)q0[0], a1 = (float)q0[1], a2 = (float)q1[0], a3 = (float)q1[1];
  float a4 = (float)q2[0], a5 = (float)q2[1], a6 = (float)q3[0], a7 = (float)q3[1];
#define RED8(x) x += __shfl_xor(x, 8); x += __shfl_xor(x, 16); x += __shfl_xor(x, 32);
  RED8(a0) RED8(a1) RED8(a2) RED8(a3) RED8(a4) RED8(a5) RED8(a6) RED8(a7)
#undef RED8
  if (g == 0) {
    float di = dinv[node];
    const float4* sp = (const float4*)(self2 + (size_t)node * 64);
    float4 s0v = sp[c * 2], s1v = sp[c * 2 + 1];
    float4 o0 = {s0v.x + a0 * di, s0v.y + a1 * di, s0v.z + a2 * di, s0v.w + a3 * di};
    float4 o1 = {s1v.x + a4 * di, s1v.y + a5 * di, s1v.z + a6 * di, s1v.w + a7 * di};
    float4* op = (float4*)(out + (size_t)node * 64);
    op[c * 2] = o0;
    op[c * 2 + 1] = o1;
  }
}

// ---------------- MFMA GEMM (f16): OUT = act([A0|A1] @ WT^T + B), layers 0/1 ----------------
template <int NOUT, bool RELU>
__global__ __launch_bounds__(256, 4) void k_mm(
    const unsigned short* __restrict__ A0, const unsigned short* __restrict__ A1,
    const unsigned short* __restrict__ WT, const float* __restrict__ Bv,
    unsigned short* __restrict__ OUT) {
  constexpr int NFC = NOUT / 64;
  __shared__ __align__(16) unsigned short sm[16896];  // 33792 B
  const int row0 = blockIdx.x * 64;
  const int tid = threadIdx.x;

  for (int i = tid; i < 1024; i += 256) {
    int r = i >> 4, c = i & 15;
    int gr = row0 + r;
    if (gr >= N_NODES) gr = N_NODES - 1;
    *(uint4*)(sm + r * 264 + c * 8) = ((const uint4*)(A0 + (size_t)gr * 128))[c];
    *(uint4*)(sm + r * 264 + 128 + c * 8) = ((const uint4*)(A1 + (size_t)gr * 128))[c];
  }

  const int lane = tid & 63;
  const int w = tid >> 6;
  const int r16 = lane & 15;
  const int kg = lane >> 4;
  const int wc0 = w * (NOUT / 4);

  f32x4 acc[4][NFC];
#pragma unroll
  for (int rf = 0; rf < 4; rf++)
#pragma unroll
    for (int cf = 0; cf < NFC; cf++) acc[rf][cf] = (f32x4){0.f, 0.f, 0.f, 0.f};

  __syncthreads();

  const unsigned short* wtb = WT + (size_t)(wc0 + r16) * 256 + kg * 8;
  const unsigned short* asb = sm + r16 * 264 + kg * 8;

  for (int ks = 0; ks < 8; ks++) {
    f16x8 a[4];
#pragma unroll
    for (int rf = 0; rf < 4; rf++)
      a[rf] = *(const f16x8*)(asb + rf * 16 * 264 + ks * 32);
#pragma unroll
    for (int cf = 0; cf < NFC; cf++) {
      f16x8 b = *(const f16x8*)(wtb + cf * 16 * 256 + ks * 32);
#pragma unroll
      for (int rf = 0; rf < 4; rf++)
        acc[rf][cf] = __builtin_amdgcn_mfma_f32_16x16x32_f16(a[rf], b, acc[rf][cf], 0, 0, 0);
    }
  }

  __syncthreads();  // reuse sm for output staging

  constexpr int LSO = NOUT + 8;
  unsigned short* so = sm;
#pragma unroll
  for (int rf = 0; rf < 4; rf++)
#pragma unroll
    for (int cf = 0; cf < NFC; cf++) {
      int col = wc0 + cf * 16 + r16;
      float bias = Bv[col];
#pragma unroll
      for (int r = 0; r < 4; r++) {
        int row = rf * 16 + kg * 4 + r;
        float v = acc[rf][cf][r] + bias;
        if (RELU) v = fmaxf(v, 0.f);
        so[row * LSO + col] = f2h(v);
      }
    }
  __syncthreads();
  for (int i = tid; i < 64 * (NOUT / 8); i += 256) {
    int r = i / (NOUT / 8), c = i % (NOUT / 8);
    int gr = row0 + r;
    if (gr < N_NODES)
      *(uint4*)(OUT + (size_t)gr * NOUT + c * 8) = *(const uint4*)(so + r * LSO + c * 8);
  }
}

// ---------------- layer-2 GEMM: h2 (K=128) @ [Ws2|Wn2] -> self2 (fp32,+bias) & zn (f16) ----------------
__global__ __launch_bounds__(256, 4) void k_mm2(
    const unsigned short* __restrict__ A, const unsigned short* __restrict__ WT,
    const float* __restrict__ Bv, float* __restrict__ SELF,
    unsigned short* __restrict__ ZN) {
  __shared__ __align__(16) unsigned short sm[64 * 136];  // 17408 B
  const int row0 = blockIdx.x * 64;
  const int tid = threadIdx.x;

  for (int i = tid; i < 1024; i += 256) {
    int r = i >> 4, c = i & 15;
    int gr = row0 + r;
    if (gr >= N_NODES) gr = N_NODES - 1;
    *(uint4*)(sm + r * 136 + c * 8) = ((const uint4*)(A + (size_t)gr * 128))[c];
  }

  const int lane = tid & 63;
  const int w = tid >> 6;
  const int r16 = lane & 15;
  const int kg = lane >> 4;
  const int wc0 = w * 32;

  f32x4 acc[4][2];
#pragma unroll
  for (int rf = 0; rf < 4; rf++)
#pragma unroll
    for (int cf = 0; cf < 2; cf++) acc[rf][cf] = (f32x4){0.f, 0.f, 0.f, 0.f};

  __syncthreads();

  const unsigned short* wtb = WT + (size_t)(wc0 + r16) * 128 + kg * 8;
  const unsigned short* asb = sm + r16 * 136 + kg * 8;

  for (int ks = 0; ks < 4; ks++) {
    f16x8 a[4];
#pragma unroll
    for (int rf = 0; rf < 4; rf++)
      a[rf] = *(const f16x8*)(asb + rf * 16 * 136 + ks * 32);
#pragma unroll
    for (int cf = 0; cf < 2; cf++) {
      f16x8 b = *(const f16x8*)(wtb + cf * 16 * 128 + ks * 32);
#pragma unroll
      for (int rf = 0; rf < 4; rf++)
        acc[rf][cf] = __builtin_amdgcn_mfma_f32_16x16x32_f16(a[rf], b, acc[rf][cf], 0, 0, 0);
    }
  }

  __syncthreads();

  // phase A: self (cols 0..63) fp32 + bias, staged [64][68] floats
  float* sof = (float*)sm;
#pragma unroll
  for (int rf = 0; rf < 4; rf++)
#pragma unroll
    for (int cf = 0; cf < 2; cf++) {
      int col = wc0 + cf * 16 + r16;
      if (col < 64) {
        float bias = Bv[col];
#pragma unroll
        for (int r = 0; r < 4; r++) {
          int row = rf * 16 + kg * 4 + r;
          sof[row * 68 + col] = acc[rf][cf][r] + bias;
        }
      }
    }
  __syncthreads();
  for (int i = tid; i < 1024; i += 256) {
    int r = i >> 4, c = i & 15;
    int gr = row0 + r;
    if (gr < N_NODES)
      *(float4*)(SELF + (size_t)gr * 64 + c * 4) = *(const float4*)(sof + r * 68 + c * 4);
  }
  __syncthreads();

  // phase B: zn (cols 64..127) f16, staged [64][72] ushort
  unsigned short* soh = sm;
#pragma unroll
  for (int rf = 0; rf < 4; rf++)
#pragma unroll
    for (int cf = 0; cf < 2; cf++) {
      int col = wc0 + cf * 16 + r16;
      if (col >= 64) {
#pragma unroll
        for (int r = 0; r < 4; r++) {
          int row = rf * 16 + kg * 4 + r;
          soh[row * 72 + (col - 64)] = f2h(acc[rf][cf][r]);
        }
      }
    }
  __syncthreads();
  for (int i = tid; i < 512; i += 256) {
    int r = i >> 3, c = i & 7;
    int gr = row0 + r;
    if (gr < N_NODES)
      *(uint4*)(ZN + (size_t)gr * 64 + c * 8) = *(const uint4*)(soh + r * 72 + c * 8);
  }
}

// ---------------- launch ----------------

extern "C" void kernel_launch(void* const* d_in, const int* in_sizes, int n_in,
                              void* d_out, int out_size, void* d_ws, size_t ws_size,
                              hipStream_t stream) {
  const float* x   = (const float*)d_in[0];
  const int*   src = (const int*)d_in[1];
  const int*   dst = (const int*)d_in[2];
  const float* ws0 = (const float*)d_in[3];
  const float* wn0 = (const float*)d_in[4];
  const float* b0  = (const float*)d_in[5];
  const float* ws1 = (const float*)d_in[6];
  const float* wn1 = (const float*)d_in[7];
  const float* b1  = (const float*)d_in[8];
  const float* ws2 = (const float*)d_in[9];
  const float* wn2 = (const float*)d_in[10];
  const float* b2  = (const float*)d_in[11];
  float* out = (float*)d_out;

  uint8_t* base = (uint8_t*)d_ws;
  size_t off = 0;
  auto alloc = [&](size_t bytes) -> void* {
    void* p = base + off;
    off = (off + bytes + 255) & ~(size_t)255;
    return p;
  };
  int*   rowbeg  = (int*)alloc((size_t)N_NODES * 4);
  int*   rowend  = (int*)alloc((size_t)N_NODES * 4);
  float* dinv    = (float*)alloc((size_t)N_NODES * 4);
  int*   csr     = (int*)alloc((size_t)NB * CAP * 4);            // 6.4 MB arena
  unsigned int* stage = (unsigned int*)alloc((size_t)NB * CAP * 4);
  int*   hcnt    = (int*)alloc((size_t)512 * NB * 4);            // [blk][bucket]
  int*   hoff    = (int*)alloc((size_t)NB * 512 * 4);            // [bucket][blk]
  int*   bcnt    = (int*)alloc((size_t)NB * 4);
  unsigned short* xb  = (unsigned short*)alloc((size_t)N_NODES * 128 * 2);
  unsigned short* nmb = (unsigned short*)alloc((size_t)N_NODES * 128 * 2);
  unsigned short* h1b = (unsigned short*)alloc((size_t)N_NODES * 128 * 2);
  unsigned short* h2b = (unsigned short*)alloc((size_t)N_NODES * 128 * 2);
  float* self2 = (float*)alloc((size_t)N_NODES * 64 * 4);
  unsigned short* znb = (unsigned short*)alloc((size_t)N_NODES * 64 * 2);
  unsigned short* wt0 = (unsigned short*)alloc(128 * 256 * 2);
  unsigned short* wt1 = (unsigned short*)alloc(128 * 256 * 2);
  unsigned short* wt2 = (unsigned short*)alloc(128 * 128 * 2);

  k_count_prep<<<SCB + PREPB, 256, 0, stream>>>(dst, hcnt, x, xb, ws0, wn0, wt0,
                                                ws1, wn1, wt1, ws2, wn2, wt2);
  k_hscan<<<NB, 512, 0, stream>>>(hcnt, hoff, bcnt);
  k_scatter<<<SCB, 256, 0, stream>>>(src, dst, hoff, stage);
  k_bucket<<<NB, 256, 0, stream>>>(stage, bcnt, csr, rowbeg, rowend, dinv);

  const int GMM = (N_NODES + 63) / 64;  // 1563

  // layer 0
  k_agg<<<25000, 256, 0, stream>>>(xb, rowbeg, rowend, csr, dinv, nmb);
  k_mm<128, true><<<GMM, 256, 0, stream>>>(xb, nmb, wt0, b0, h1b);
  // layer 1
  k_agg<<<25000, 256, 0, stream>>>(h1b, rowbeg, rowend, csr, dinv, nmb);
  k_mm<128, true><<<GMM, 256, 0, stream>>>(h1b, nmb, wt1, b1, h2b);
  // layer 2: transform-then-aggregate (linearity of mean)
  k_mm2<<<GMM, 256, 0, stream>>>(h2b, wt2, b2, self2, znb);
  k_agg2<<<25000, 256, 0, stream>>>(znb, rowbeg, rowend, csr, dinv, self2, out);
}

// Round 16
// 230.306 us; speedup vs baseline: 1.0651x; 1.0163x over previous
//
#include <hip/hip_runtime.h>
#include <stdint.h>

#define N_NODES 100000
#define N_EDGES 1000000
#define NB 782   // ceil(N_NODES/128) buckets of 128 nodes
#define CAP 2048 // arena slots per bucket (expected 1280, sigma 36 -> 21 sigma margin)
#define EPB 2048 // edges per count/scatter block
#define SCB ((N_EDGES + EPB - 1) / EPB)  // 489 (padded to 512 in hcnt/hoff layout)
#define PREPB 6442  // 6250 cast blocks + 192 weight blocks

typedef __attribute__((ext_vector_type(2))) _Float16 f16x2;
typedef __attribute__((ext_vector_type(8))) _Float16 f16x8;
typedef __attribute__((ext_vector_type(4))) float f32x4;

__device__ __forceinline__ unsigned short f2h(float f) {
  _Float16 h = (_Float16)f;
  return *(unsigned short*)&h;
}

// ---------------- pass A: per-block histogram (plain stores, NO global atomics) + prep ----------------
__global__ void k_count_prep(const int* __restrict__ dst, int* __restrict__ hcnt,
                             const float* __restrict__ x, unsigned short* __restrict__ xb,
                             const float* __restrict__ ws0, const float* __restrict__ wn0,
                             unsigned short* __restrict__ wt0,
                             const float* __restrict__ ws1, const float* __restrict__ wn1,
                             unsigned short* __restrict__ wt1,
                             const float* __restrict__ ws2, const float* __restrict__ wn2,
                             unsigned short* __restrict__ wt2) {
  __shared__ int h[NB];
  int t = threadIdx.x;
  if (blockIdx.x < SCB) {
    for (int i = t; i < NB; i += 256) h[i] = 0;
    __syncthreads();
    int base = blockIdx.x * EPB;
#pragma unroll 8
    for (int k = 0; k < EPB / 256; k++) {
      int i = base + t + k * 256;
      if (i < N_EDGES) atomicAdd(&h[dst[i] >> 7], 1);
    }
    __syncthreads();
    int* hrow = hcnt + (size_t)blockIdx.x * NB;  // coalesced 782-int row
    for (int i = t; i < NB; i += 256) hrow[i] = h[i];
    return;
  }
  int b = blockIdx.x - SCB;
  if (b < 6250) {
    int i = b * 256 + t;  // 6250*256 == N_NODES*16 exactly
    float4 a = ((const float4*)x)[2 * i];
    float4 v = ((const float4*)x)[2 * i + 1];
    unsigned short r[8] = {f2h(a.x), f2h(a.y), f2h(a.z), f2h(a.w),
                           f2h(v.x), f2h(v.y), f2h(v.z), f2h(v.w)};
    *(uint4*)(xb + (size_t)i * 8) = *(uint4*)r;
    return;
  }
  int w = (b - 6250) * 256 + t;  // 0 .. 49151
  if (w < 16384) {  // wt0: [n][256] = [Ws0^T | Wn0^T]
    int n = w >> 7, k = w & 127;
    wt0[n * 256 + k] = f2h(ws0[(size_t)k * 128 + n]);
    wt0[n * 256 + 128 + k] = f2h(wn0[(size_t)k * 128 + n]);
  } else if (w < 32768) {  // wt1
    w -= 16384;
    int n = w >> 7, k = w & 127;
    wt1[n * 256 + k] = f2h(ws1[(size_t)k * 128 + n]);
    wt1[n * 256 + 128 + k] = f2h(wn1[(size_t)k * 128 + n]);
  } else {  // wt2: [n][128], n<64 -> Ws2 col n ; n>=64 -> Wn2 col n-64 (K=128)
    w -= 32768;
    int n = w >> 7, k = w & 127;
    float v = (n < 64) ? ws2[(size_t)k * 64 + n] : wn2[(size_t)k * 64 + (n - 64)];
    wt2[n * 128 + k] = f2h(v);
  }
}

// ---------------- pass B: per-bucket exclusive scan across blocks -> cursors + totals ----------------
__global__ __launch_bounds__(512) void k_hscan(const int* __restrict__ hcnt,
                                               int* __restrict__ hoff,
                                               int* __restrict__ bcnt) {
  __shared__ int sc[512];
  int bucket = blockIdx.x, t = threadIdx.x;
  int v = (t < SCB) ? hcnt[(size_t)t * NB + bucket] : 0;
  sc[t] = v;
  __syncthreads();
  for (int off = 1; off < 512; off <<= 1) {
    int a = (t >= off) ? sc[t - off] : 0;
    __syncthreads();
    sc[t] += a;
    __syncthreads();
  }
  hoff[(size_t)bucket * 512 + t] = sc[t] - v;  // exclusive prefix, coalesced
  if (t == 511) bcnt[bucket] = sc[511];
}

// ---------------- pass C: scatter into chunked arena (cursors from hoff, LDS-only atomics) ----------------
__global__ void k_scatter(const int* __restrict__ src, const int* __restrict__ dst,
                          const int* __restrict__ hoff, unsigned int* __restrict__ stage) {
  __shared__ int cur[NB];
  int t = threadIdx.x;
  int blk = blockIdx.x;
  for (int i = t; i < NB; i += 256) cur[i] = hoff[(size_t)i * 512 + blk];
  __syncthreads();
  int base = blk * EPB;
#pragma unroll 8
  for (int k = 0; k < EPB / 256; k++) {
    int i = base + t + k * 256;
    if (i < N_EDGES) {
      int d = dst[i];
      int b = d >> 7;
      int pos = atomicAdd(&cur[b], 1);
      stage[(size_t)b * CAP + pos] = ((unsigned int)(d & 127) << 17) | (unsigned int)src[i];
    }
  }
}

// ---------------- per-bucket: group by node within arena chunk ----------------
// writes rowinfo[node] = (rowbeg, deg) as one int2 (single 8B header load in agg)
__global__ void k_bucket(const unsigned int* __restrict__ stage, const int* __restrict__ bcnt,
                         int* __restrict__ csr, int2* __restrict__ rowinfo) {
  __shared__ int cnt[128], sc[128], cur[128];
  int b = blockIdx.x, t = threadIdx.x;
  int nb = bcnt[b];
  const unsigned int* sb = stage + (size_t)b * CAP;
  int e0 = b * CAP;
  if (t < 128) cnt[t] = 0;
  __syncthreads();
  for (int e = t; e < nb; e += 256)
    atomicAdd(&cnt[sb[e] >> 17], 1);
  __syncthreads();
  int myc = (t < 128) ? cnt[t] : 0;
  if (t < 128) sc[t] = myc;
  __syncthreads();
  for (int off = 1; off < 128; off <<= 1) {
    int a = (t < 128 && t >= off) ? sc[t - off] : 0;
    __syncthreads();
    if (t < 128) sc[t] += a;
    __syncthreads();
  }
  if (t < 128) {
    int node = b * 128 + t;
    int ex = sc[t] - myc;
    cur[t] = ex;
    if (node < N_NODES) {
      int2 ri;
      ri.x = e0 + ex;
      ri.y = myc;
      rowinfo[node] = ri;
    }
  }
  __syncthreads();
  for (int e = t; e < nb; e += 256) {
    unsigned int v = sb[e];
    int l = v >> 17;
    int pos = e0 + atomicAdd(&cur[l], 1);
    csr[pos] = (int)(v & 0x1FFFFu);
  }
}

// ---------------- aggregation (128-dim f16 rows): wave/node, 16 slots ----------------
// 128-thread blocks (2 waves): R14 lesson inverted - finer granularity means a
// slow wave strands 1 sibling slot not 3. One int2 header load per wave;
// dinv computed in-kernel (exact fp32 div == precomputed value).
__global__ void k_agg(const unsigned short* __restrict__ feat,
                      const int2* __restrict__ rowinfo, const int* __restrict__ csr,
                      unsigned short* __restrict__ nm) {
  int wv = threadIdx.x >> 6, lane = threadIdx.x & 63;
  int node = blockIdx.x * 2 + wv;
  if (node >= N_NODES) return;
  const uint4* fp = (const uint4*)feat;  // 16 uint4 per feature row
  int2 ri = rowinfo[node];
  int s0 = ri.x, s1 = ri.x + ri.y;
  int g = lane >> 4, c = lane & 15;
  f16x2 q0 = {0, 0}, q1 = {0, 0}, q2 = {0, 0}, q3 = {0, 0};
  for (int j = s0 + g; j < s1; j += 16) {
    int i1 = j + 4, i2 = j + 8, i3 = j + 12;
    bool h1 = i1 < s1, h2 = i2 < s1, h3 = i3 < s1;
    int c0 = csr[j];
    int c1 = h1 ? csr[i1] : 0;
    int c2 = h2 ? csr[i2] : 0;
    int c3 = h3 ? csr[i3] : 0;
    uint4 v0, v1, v2, v3;
    v0 = fp[(size_t)c0 * 16 + c];
    if (h1) v1 = fp[(size_t)c1 * 16 + c];
    if (h2) v2 = fp[(size_t)c2 * 16 + c];
    if (h3) v3 = fp[(size_t)c3 * 16 + c];
    q0 += *(const f16x2*)&v0.x; q1 += *(const f16x2*)&v0.y;
    q2 += *(const f16x2*)&v0.z; q3 += *(const f16x2*)&v0.w;
    if (h1) {
      q0 += *(const f16x2*)&v1.x; q1 += *(const f16x2*)&v1.y;
      q2 += *(const f16x2*)&v1.z; q3 += *(const f16x2*)&v1.w;
    }
    if (h2) {
      q0 += *(const f16x2*)&v2.x; q1 += *(const f16x2*)&v2.y;
      q2 += *(const f16x2*)&v2.z; q3 += *(const f16x2*)&v2.w;
    }
    if (h3) {
      q0 += *(const f16x2*)&v3.x; q1 += *(const f16x2*)&v3.y;
      q2 += *(const f16x2*)&v3.z; q3 += *(const f16x2*)&v3.w;
    }
  }
  float a0 = (float)q0[0], a1 = (float)q0[1], a2 = (float)q1[0], a3 = (float)q1[1];
  float a4 = (float)q2[0], a5 = (float)q2[1], a6 = (float)q3[0], a7 = (float)q3[1];
#define RED(x) x += __shfl_xor(x, 16); x += __shfl_xor(x, 32);
  RED(a0) RED(a1) RED(a2) RED(a3) RED(a4) RED(a5) RED(a6) RED(a7)
#undef RED
  if (g == 0) {
    float di = ri.y ? 1.0f / (float)ri.y : 0.0f;
    uint4 o;
    o.x = ((unsigned int)f2h(a1 * di) << 16) | (unsigned int)f2h(a0 * di);
    o.y = ((unsigned int)f2h(a3 * di) << 16) | (unsigned int)f2h(a2 * di);
    o.z = ((unsigned int)f2h(a5 * di) << 16) | (unsigned int)f2h(a4 * di);
    o.w = ((unsigned int)f2h(a7 * di) << 16) | (unsigned int)f2h(a6 * di);
    ((uint4*)(nm + (size_t)node * 128))[c] = o;
  }
}

// ---------------- layer-2 aggregation of z (64-dim f16 rows) + self add, fp32 out ----------------
__global__ void k_agg2(const unsigned short* __restrict__ zn,
                       const int2* __restrict__ rowinfo, const int* __restrict__ csr,
                       const float* __restrict__ self2, float* __restrict__ out) {
  int wv = threadIdx.x >> 6, lane = threadIdx.x & 63;
  int node = blockIdx.x * 2 + wv;
  if (node >= N_NODES) return;
  const uint4* fp = (const uint4*)zn;  // 8 uint4 per row
  int2 ri = rowinfo[node];
  int s0 = ri.x, s1 = ri.x + ri.y;
  int g = lane >> 3, c = lane & 7;
  f16x2 q0 = {0, 0}, q1 = {0, 0}, q2 = {0, 0}, q3 = {0, 0};
  for (int j = s0 + g; j < s1; j += 32) {
    int i1 = j + 8, i2 = j + 16, i3 = j + 24;
    bool h1 = i1 < s1, h2 = i2 < s1, h3 = i3 < s1;
    int c0 = csr[j];
    int c1 = h1 ? csr[i1] : 0;
    int c2 = h2 ? csr[i2] : 0;
    int c3 = h3 ? csr[i3] : 0;
    uint4 v0, v1, v2, v3;
    v0 = fp[(size_t)c0 * 8 + c];
    if (h1) v1 = fp[(size_t)c1 * 8 + c];
    if (h2) v2 = fp[(size_t)c2 * 8 + c];
    if (h3) v3 = fp[(size_t)c3 * 8 + c];
    q0 += *(const f16x2*)&v0.x; q1 += *(const f16x2*)&v0.y;
    q2 += *(const f16x2*)&v0.z; q3 += *(const f16x2*)&v0.w;
    if (h1) {
      q0 += *(const f16x2*)&v1.x; q1 += *(const f16x2*)&v1.y;
      q2 += *(const f16x2*)&v1.z; q3 += *(const f16x2*)&v1.w;
    }
    if (h2) {
      q0 += *(const f16x2*)&v2.x; q1 += *(const f16x2*)&v2.y;
      q2 += *(const f16x2*)&v2.z; q3 += *(const f16x2*)&v2.w;
    }
    if (h3) {
      q0 += *(const f16x2*)&v3.x; q1 += *(const f16x2*)&v3.y;
      q2 += *(const f16x2*)&v3.z; q3 += *(const f16x2*)&v3.w;
    }
  }
  float a0 = (float)q0[0], a1 = (float)q0[1], a2 = (float)q1[0], a3 = (float)q1[1];
  float a4 = (float)q2[0], a5 = (float)q2[1], a6 = (float)q3[0], a7 = (float)q3[1];
#define RED8(x) x += __shfl_xor(x, 8); x += __shfl_xor(x, 16); x += __shfl_xor(x, 32);
  RED8(a0) RED8(a1) RED8(a2) RED8(a3) RED8(a4) RED8(a5) RED8(a6) RED8(a7)
#undef RED8
  if (g == 0) {
    float di = ri.y ? 1.0f / (float)ri.y : 0.0f;
    const float4* sp = (const float4*)(self2 + (size_t)node * 64);
    float4 s0v = sp[c * 2], s1v = sp[c * 2 + 1];
    float4 o0 = {s0v.x + a0 * di, s0v.y + a1 * di, s0v.z + a2 * di, s0v.w + a3 * di};
    float4 o1 = {s1v.x + a4 * di, s1v.y + a5 * di, s1v.z + a6 * di, s1v.w + a7 * di};
    float4* op = (float4*)(out + (size_t)node * 64);
    op[c * 2] = o0;
    op[c * 2 + 1] = o1;
  }
}

// ---------------- MFMA GEMM (f16): OUT = act([A0|A1] @ WT^T + B), layers 0/1 ----------------
template <int NOUT, bool RELU>
__global__ __launch_bounds__(256, 4) void k_mm(
    const unsigned short* __restrict__ A0, const unsigned short* __restrict__ A1,
    const unsigned short* __restrict__ WT, const float* __restrict__ Bv,
    unsigned short* __restrict__ OUT) {
  constexpr int NFC = NOUT / 64;
  __shared__ __align__(16) unsigned short sm[16896];  // 33792 B
  const int row0 = blockIdx.x * 64;
  const int tid = threadIdx.x;

  for (int i = tid; i < 1024; i += 256) {
    int r = i >> 4, c = i & 15;
    int gr = row0 + r;
    if (gr >= N_NODES) gr = N_NODES - 1;
    *(uint4*)(sm + r * 264 + c * 8) = ((const uint4*)(A0 + (size_t)gr * 128))[c];
    *(uint4*)(sm + r * 264 + 128 + c * 8) = ((const uint4*)(A1 + (size_t)gr * 128))[c];
  }

  const int lane = tid & 63;
  const int w = tid >> 6;
  const int r16 = lane & 15;
  const int kg = lane >> 4;
  const int wc0 = w * (NOUT / 4);

  f32x4 acc[4][NFC];
#pragma unroll
  for (int rf = 0; rf < 4; rf++)
#pragma unroll
    for (int cf = 0; cf < NFC; cf++) acc[rf][cf] = (f32x4){0.f, 0.f, 0.f, 0.f};

  __syncthreads();

  const unsigned short* wtb = WT + (size_t)(wc0 + r16) * 256 + kg * 8;
  const unsigned short* asb = sm + r16 * 264 + kg * 8;

  for (int ks = 0; ks < 8; ks++) {
    f16x8 a[4];
#pragma unroll
    for (int rf = 0; rf < 4; rf++)
      a[rf] = *(const f16x8*)(asb + rf * 16 * 264 + ks * 32);
#pragma unroll
    for (int cf = 0; cf < NFC; cf++) {
      f16x8 b = *(const f16x8*)(wtb + cf * 16 * 256 + ks * 32);
#pragma unroll
      for (int rf = 0; rf < 4; rf++)
        acc[rf][cf] = __builtin_amdgcn_mfma_f32_16x16x32_f16(a[rf], b, acc[rf][cf], 0, 0, 0);
    }
  }

  __syncthreads();  // reuse sm for output staging

  constexpr int LSO = NOUT + 8;
  unsigned short* so = sm;
#pragma unroll
  for (int rf = 0; rf < 4; rf++)
#pragma unroll
    for (int cf = 0; cf < NFC; cf++) {
      int col = wc0 + cf * 16 + r16;
      float bias = Bv[col];
#pragma unroll
      for (int r = 0; r < 4; r++) {
        int row = rf * 16 + kg * 4 + r;
        float v = acc[rf][cf][r] + bias;
        if (RELU) v = fmaxf(v, 0.f);
        so[row * LSO + col] = f2h(v);
      }
    }
  __syncthreads();
  for (int i = tid; i < 64 * (NOUT / 8); i += 256) {
    int r = i / (NOUT / 8), c = i % (NOUT / 8);
    int gr = row0 + r;
    if (gr < N_NODES)
      *(uint4*)(OUT + (size_t)gr * NOUT + c * 8) = *(const uint4*)(so + r * LSO + c * 8);
  }
}

// ---------------- layer-2 GEMM: h2 (K=128) @ [Ws2|Wn2] -> self2 (fp32,+bias) & zn (f16) ----------------
__global__ __launch_bounds__(256, 4) void k_mm2(
    const unsigned short* __restrict__ A, const unsigned short* __restrict__ WT,
    const float* __restrict__ Bv, float* __restrict__ SELF,
    unsigned short* __restrict__ ZN) {
  __shared__ __align__(16) unsigned short sm[64 * 136];  // 17408 B
  const int row0 = blockIdx.x * 64;
  const int tid = threadIdx.x;

  for (int i = tid; i < 1024; i += 256) {
    int r = i >> 4, c = i & 15;
    int gr = row0 + r;
    if (gr >= N_NODES) gr = N_NODES - 1;
    *(uint4*)(sm + r * 136 + c * 8) = ((const uint4*)(A + (size_t)gr * 128))[c];
  }

  const int lane = tid & 63;
  const int w = tid >> 6;
  const int r16 = lane & 15;
  const int kg = lane >> 4;
  const int wc0 = w * 32;

  f32x4 acc[4][2];
#pragma unroll
  for (int rf = 0; rf < 4; rf++)
#pragma unroll
    for (int cf = 0; cf < 2; cf++) acc[rf][cf] = (f32x4){0.f, 0.f, 0.f, 0.f};

  __syncthreads();

  const unsigned short* wtb = WT + (size_t)(wc0 + r16) * 128 + kg * 8;
  const unsigned short* asb = sm + r16 * 136 + kg * 8;

  for (int ks = 0; ks < 4; ks++) {
    f16x8 a[4];
#pragma unroll
    for (int rf = 0; rf < 4; rf++)
      a[rf] = *(const f16x8*)(asb + rf * 16 * 136 + ks * 32);
#pragma unroll
    for (int cf = 0; cf < 2; cf++) {
      f16x8 b = *(const f16x8*)(wtb + cf * 16 * 128 + ks * 32);
#pragma unroll
      for (int rf = 0; rf < 4; rf++)
        acc[rf][cf] = __builtin_amdgcn_mfma_f32_16x16x32_f16(a[rf], b, acc[rf][cf], 0, 0, 0);
    }
  }

  __syncthreads();

  // phase A: self (cols 0..63) fp32 + bias, staged [64][68] floats
  float* sof = (float*)sm;
#pragma unroll
  for (int rf = 0; rf < 4; rf++)
#pragma unroll
    for (int cf = 0; cf < 2; cf++) {
      int col = wc0 + cf * 16 + r16;
      if (col < 64) {
        float bias = Bv[col];
#pragma unroll
        for (int r = 0; r < 4; r++) {
          int row = rf * 16 + kg * 4 + r;
          sof[row * 68 + col] = acc[rf][cf][r] + bias;
        }
      }
    }
  __syncthreads();
  for (int i = tid; i < 1024; i += 256) {
    int r = i >> 4, c = i & 15;
    int gr = row0 + r;
    if (gr < N_NODES)
      *(float4*)(SELF + (size_t)gr * 64 + c * 4) = *(const float4*)(sof + r * 68 + c * 4);
  }
  __syncthreads();

  // phase B: zn (cols 64..127) f16, staged [64][72] ushort
  unsigned short* soh = sm;
#pragma unroll
  for (int rf = 0; rf < 4; rf++)
#pragma unroll
    for (int cf = 0; cf < 2; cf++) {
      int col = wc0 + cf * 16 + r16;
      if (col >= 64) {
#pragma unroll
        for (int r = 0; r < 4; r++) {
          int row = rf * 16 + kg * 4 + r;
          soh[row * 72 + (col - 64)] = f2h(acc[rf][cf][r]);
        }
      }
    }
  __syncthreads();
  for (int i = tid; i < 512; i += 256) {
    int r = i >> 3, c = i & 7;
    int gr = row0 + r;
    if (gr < N_NODES)
      *(uint4*)(ZN + (size_t)gr * 64 + c * 8) = *(const uint4*)(soh + r * 72 + c * 8);
  }
}

// ---------------- launch ----------------

extern "C" void kernel_launch(void* const* d_in, const int* in_sizes, int n_in,
                              void* d_out, int out_size, void* d_ws, size_t ws_size,
                              hipStream_t stream) {
  const float* x   = (const float*)d_in[0];
  const int*   src = (const int*)d_in[1];
  const int*   dst = (const int*)d_in[2];
  const float* ws0 = (const float*)d_in[3];
  const float* wn0 = (const float*)d_in[4];
  const float* b0  = (const float*)d_in[5];
  const float* ws1 = (const float*)d_in[6];
  const float* wn1 = (const float*)d_in[7];
  const float* b1  = (const float*)d_in[8];
  const float* ws2 = (const float*)d_in[9];
  const float* wn2 = (const float*)d_in[10];
  const float* b2  = (const float*)d_in[11];
  float* out = (float*)d_out;

  uint8_t* base = (uint8_t*)d_ws;
  size_t off = 0;
  auto alloc = [&](size_t bytes) -> void* {
    void* p = base + off;
    off = (off + bytes + 255) & ~(size_t)255;
    return p;
  };
  int2*  rowinfo = (int2*)alloc((size_t)N_NODES * 8);
  int*   csr     = (int*)alloc((size_t)NB * CAP * 4);            // 6.4 MB arena
  unsigned int* stage = (unsigned int*)alloc((size_t)NB * CAP * 4);
  int*   hcnt    = (int*)alloc((size_t)512 * NB * 4);            // [blk][bucket]
  int*   hoff    = (int*)alloc((size_t)NB * 512 * 4);            // [bucket][blk]
  int*   bcnt    = (int*)alloc((size_t)NB * 4);
  unsigned short* xb  = (unsigned short*)alloc((size_t)N_NODES * 128 * 2);
  unsigned short* nmb = (unsigned short*)alloc((size_t)N_NODES * 128 * 2);
  unsigned short* h1b = (unsigned short*)alloc((size_t)N_NODES * 128 * 2);
  unsigned short* h2b = (unsigned short*)alloc((size_t)N_NODES * 128 * 2);
  float* self2 = (float*)alloc((size_t)N_NODES * 64 * 4);
  unsigned short* znb = (unsigned short*)alloc((size_t)N_NODES * 64 * 2);
  unsigned short* wt0 = (unsigned short*)alloc(128 * 256 * 2);
  unsigned short* wt1 = (unsigned short*)alloc(128 * 256 * 2);
  unsigned short* wt2 = (unsigned short*)alloc(128 * 128 * 2);

  k_count_prep<<<SCB + PREPB, 256, 0, stream>>>(dst, hcnt, x, xb, ws0, wn0, wt0,
                                                ws1, wn1, wt1, ws2, wn2, wt2);
  k_hscan<<<NB, 512, 0, stream>>>(hcnt, hoff, bcnt);
  k_scatter<<<SCB, 256, 0, stream>>>(src, dst, hoff, stage);
  k_bucket<<<NB, 256, 0, stream>>>(stage, bcnt, csr, rowinfo);

  const int GMM = (N_NODES + 63) / 64;  // 1563
  const int GAGG = N_NODES / 2;         // 50000 blocks x 2 waves (exact)

  // layer 0
  k_agg<<<GAGG, 128, 0, stream>>>(xb, rowinfo, csr, nmb);
  k_mm<128, true><<<GMM, 256, 0, stream>>>(xb, nmb, wt0, b0, h1b);
  // layer 1
  k_agg<<<GAGG, 128, 0, stream>>>(h1b, rowinfo, csr, nmb);
  k_mm<128, true><<<GMM, 256, 0, stream>>>(h1b, nmb, wt1, b1, h2b);
  // layer 2: transform-then-aggregate (linearity of mean)
  k_mm2<<<GMM, 256, 0, stream>>>(h2b, wt2, b2, self2, znb);
  k_agg2<<<GAGG, 128, 0, stream>>>(znb, rowinfo, csr, self2, out);
}